// Round 1
// baseline (16623.820 us; speedup 1.0000x reference)
//
#include <hip/hip_runtime.h>
#include <math.h>

#define DEVFN __device__ __forceinline__

namespace {

constexpr int T  = 28;
constexpr int B  = 16384;
constexpr int X  = 28;
constexpr int H  = 100;
constexpr int Z  = 16;

constexpr int ROWS = 64;    // batch rows per block  (256 blocks, one per CU)
constexpr int NTH  = 512;   // 8 waves
constexpr int KP   = 102;   // LDS stride for H-sized activation rows (even -> aligned float2, low bank conflict)
constexpr int SP   = 18;    // LDS stride for Z-sized rows
constexpr float KEPS = 1e-10f;

struct Params {
  const float *x,*eps,*Wpx,*bpx,*Wpz,*bpz,*Wp1,*bp1,*Wp_mu,*bp_mu,*Wp_sig,*bp_sig,
              *We1,*be1,*We_mu,*be_mu,*We_sig,*be_sig,*Wd1,*bd1,*Wd2,*bd2,*Wd3,*bd3,
              *Wih,*Whh,*bih,*bhh;
  float *out;
};

DEVFN float fsigmoid(float v){ return 1.f/(1.f+__expf(-v)); }
DEVFN float fsoftplus(float v){ return (v > 15.f) ? v : log1pf(__expf(v)); }
DEVFN float ftanh(float v){
  v = fminf(fmaxf(v,-15.f),15.f);
  float e = __expf(2.f*v);
  return (e-1.f)/(e+1.f);
}
DEVFN float frelu(float v){ return fmaxf(v, 0.f); }

// acc[j] += dot(actRow[0:K], W[n][0:K]) for n = ug + 8*j, W row stride WS.
// Weight addresses are wave-uniform (ug is wave-uniform) -> 1 broadcast transaction per load.
template<int K, int UJ, int WS>
DEVFN void accum_pass(const float* __restrict__ actRow, const float* __restrict__ Wg,
                      int ug, int N, float* acc)
{
  #pragma unroll 2
  for (int k0 = 0; k0 < K; k0 += 4) {
    float2 a01 = *(const float2*)(actRow + k0);
    float2 a23 = *(const float2*)(actRow + k0 + 2);
    #pragma unroll
    for (int j = 0; j < UJ; ++j) {
      int n = ug + 8*j;
      if (UJ*8 <= N || n < N) {
        const float4 w = *(const float4*)(Wg + (size_t)n*WS + k0);
        acc[j] = fmaf(a01.x, w.x, fmaf(a01.y, w.y, fmaf(a23.x, w.z, fmaf(a23.y, w.w, acc[j]))));
      }
    }
  }
}

// GRU triple pass: ar[j]+=dot(act,Wg[n]); au[j]+=dot(act,Wg[n+H]); a3[j]+=dot(act,Wg[n+2H])
template<int K, int UJ, int WS>
DEVFN void gru_pass(const float* __restrict__ actRow, const float* __restrict__ Wg,
                    int ug, float* ar, float* au, float* a3)
{
  #pragma unroll 2
  for (int k0 = 0; k0 < K; k0 += 4) {
    float2 a01 = *(const float2*)(actRow + k0);
    float2 a23 = *(const float2*)(actRow + k0 + 2);
    #pragma unroll
    for (int j = 0; j < UJ; ++j) {
      int n = ug + 8*j;
      if (n < H) {
        const float4 wr = *(const float4*)(Wg + (size_t)n*WS + k0);
        const float4 wu = *(const float4*)(Wg + (size_t)(n+H)*WS + k0);
        const float4 wn = *(const float4*)(Wg + (size_t)(n+2*H)*WS + k0);
        ar[j] = fmaf(a01.x, wr.x, fmaf(a01.y, wr.y, fmaf(a23.x, wr.z, fmaf(a23.y, wr.w, ar[j]))));
        au[j] = fmaf(a01.x, wu.x, fmaf(a01.y, wu.y, fmaf(a23.x, wu.z, fmaf(a23.y, wu.w, au[j]))));
        a3[j] = fmaf(a01.x, wn.x, fmaf(a01.y, wn.y, fmaf(a23.x, wn.z, fmaf(a23.y, wn.w, a3[j]))));
      }
    }
  }
}

__global__ __launch_bounds__(NTH, 2) void vrnn_kernel(Params P)
{
  __shared__ float sh_h [ROWS*KP];
  __shared__ float sh_px[ROWS*KP];
  __shared__ float sh_pz[ROWS*KP];
  __shared__ float sh_t1[ROWS*KP];   // he -> hd1
  __shared__ float sh_t2[ROWS*KP];   // hp -> hd2
  __shared__ float sh_mu_e [ROWS*SP];
  __shared__ float sh_sig_e[ROWS*SP];
  __shared__ float sh_mu_p [ROWS*SP];
  __shared__ float sh_sig_p[ROWS*SP];
  __shared__ float sh_z    [ROWS*SP];
  __shared__ float sh_red[16];

  const int tid = threadIdx.x;
  const int row = tid & 63;        // lane index == local batch row
  const int ug  = tid >> 6;        // 0..7, wave-uniform unit group
  const int gr  = blockIdx.x * ROWS + row;

  for (int i = tid; i < ROWS*KP; i += NTH) sh_h[i] = 0.f;   // h0 = 0
  __syncthreads();

  float kl_acc = 0.f, nll_acc = 0.f;

  for (int t = 0; t < T; ++t) {
    const float* xrow = P.x + ((size_t)t*B + gr)*X;

    // ---- px = relu(x @ Wpx^T + bpx)
    {
      float acc[13] = {};
      accum_pass<X,13,X>(xrow, P.Wpx, ug, H, acc);
      #pragma unroll
      for (int j = 0; j < 13; ++j) {
        int n = ug + 8*j;
        if (n < H) sh_px[row*KP+n] = frelu(acc[j] + P.bpx[n]);
      }
    }
    __syncthreads();

    // ---- he = relu([px,h] @ We1^T + be1) -> t1
    {
      float acc[13] = {};
      accum_pass<H,13,2*H>(&sh_px[row*KP], P.We1,     ug, H, acc);
      accum_pass<H,13,2*H>(&sh_h [row*KP], P.We1 + H, ug, H, acc);
      #pragma unroll
      for (int j = 0; j < 13; ++j) {
        int n = ug + 8*j;
        if (n < H) sh_t1[row*KP+n] = frelu(acc[j] + P.be1[n]);
      }
    }
    __syncthreads();

    // ---- enc_mu/enc_sig from t1 ; hp = relu(h@Wp1^T+bp1) -> t2
    {
      float am[2] = {}, as[2] = {};
      accum_pass<H,2,H>(&sh_t1[row*KP], P.We_mu,  ug, Z, am);
      accum_pass<H,2,H>(&sh_t1[row*KP], P.We_sig, ug, Z, as);
      #pragma unroll
      for (int j = 0; j < 2; ++j) {
        int n = ug + 8*j;
        sh_mu_e [row*SP+n] = am[j] + P.be_mu[n];
        sh_sig_e[row*SP+n] = fsoftplus(as[j] + P.be_sig[n]);
      }
      float acc[13] = {};
      accum_pass<H,13,H>(&sh_h[row*KP], P.Wp1, ug, H, acc);
      #pragma unroll
      for (int j = 0; j < 13; ++j) {
        int n = ug + 8*j;
        if (n < H) sh_t2[row*KP+n] = frelu(acc[j] + P.bp1[n]);
      }
    }
    __syncthreads();

    // ---- pr_mu/pr_sig from t2 ; z = mu_e + sqrt(sig_e)*eps
    {
      float am[2] = {}, as[2] = {};
      accum_pass<H,2,H>(&sh_t2[row*KP], P.Wp_mu,  ug, Z, am);
      accum_pass<H,2,H>(&sh_t2[row*KP], P.Wp_sig, ug, Z, as);
      #pragma unroll
      for (int j = 0; j < 2; ++j) {
        int n = ug + 8*j;
        sh_mu_p [row*SP+n] = am[j] + P.bp_mu[n];
        sh_sig_p[row*SP+n] = fsoftplus(as[j] + P.bp_sig[n]);
      }
      for (int idx = tid; idx < ROWS*Z; idx += NTH) {
        int r = idx >> 4, zi = idx & 15;
        float ev = P.eps[((size_t)t*B + blockIdx.x*ROWS + r)*Z + zi];
        sh_z[r*SP+zi] = sh_mu_e[r*SP+zi] + sqrtf(sh_sig_e[r*SP+zi]) * ev;
      }
    }
    __syncthreads();

    // ---- pz = relu(z @ Wpz^T + bpz) ; KL accumulation
    {
      float acc[13] = {};
      accum_pass<Z,13,Z>(&sh_z[row*SP], P.Wpz, ug, H, acc);
      #pragma unroll
      for (int j = 0; j < 13; ++j) {
        int n = ug + 8*j;
        if (n < H) sh_pz[row*KP+n] = frelu(acc[j] + P.bpz[n]);
      }
      for (int idx = tid; idx < ROWS*Z; idx += NTH) {
        int r = idx >> 4, zi = idx & 15;
        float es = sh_sig_e[r*SP+zi];
        float ps = sh_sig_p[r*SP+zi] + KEPS;
        float dm = sh_mu_e[r*SP+zi] - sh_mu_p[r*SP+zi];
        kl_acc += 0.5f*(2.f*__logf(ps) - 2.f*__logf(es) + (es*es + dm*dm)/(ps*ps) - 1.f);
      }
    }
    __syncthreads();

    // ---- hd1 = relu([pz,h]@Wd1^T+bd1) -> t1
    {
      float acc[13] = {};
      accum_pass<H,13,2*H>(&sh_pz[row*KP], P.Wd1,     ug, H, acc);
      accum_pass<H,13,2*H>(&sh_h [row*KP], P.Wd1 + H, ug, H, acc);
      #pragma unroll
      for (int j = 0; j < 13; ++j) {
        int n = ug + 8*j;
        if (n < H) sh_t1[row*KP+n] = frelu(acc[j] + P.bd1[n]);
      }
    }
    __syncthreads();

    // ---- hd2 = relu(t1@Wd2^T+bd2) -> t2
    {
      float acc[13] = {};
      accum_pass<H,13,H>(&sh_t1[row*KP], P.Wd2, ug, H, acc);
      #pragma unroll
      for (int j = 0; j < 13; ++j) {
        int n = ug + 8*j;
        if (n < H) sh_t2[row*KP+n] = frelu(acc[j] + P.bd2[n]);
      }
    }
    __syncthreads();

    // ---- probs -> NLL ; GRU -> hnext in regs
    float hnext[13];
    {
      float ap[4] = {};
      accum_pass<H,4,H>(&sh_t2[row*KP], P.Wd3, ug, X, ap);
      #pragma unroll
      for (int j = 0; j < 4; ++j) {
        int n = ug + 8*j;
        if (n < X) {
          float p  = fsigmoid(ap[j] + P.bd3[n]);
          float xv = xrow[n];
          nll_acc -= xv*__logf(p + KEPS) + (1.f - xv)*__logf(1.f - p + KEPS);
        }
      }
      float ar[13] = {}, au[13] = {}, ai[13] = {}, ah[13] = {};
      gru_pass<H,13,2*H>(&sh_pz[row*KP], P.Wih,     ug, ar, au, ai);  // gi from pz (cols 0:100)
      gru_pass<H,13,2*H>(&sh_px[row*KP], P.Wih + H, ug, ar, au, ai);  // gi from px (cols 100:200)
      gru_pass<H,13,H>  (&sh_h [row*KP], P.Whh,     ug, ar, au, ah);  // gh from h
      #pragma unroll
      for (int j = 0; j < 13; ++j) {
        int n = ug + 8*j;
        if (n < H) {
          float r  = fsigmoid(ar[j] + P.bih[n]     + P.bhh[n]);
          float u  = fsigmoid(au[j] + P.bih[n+H]   + P.bhh[n+H]);
          float nn = ftanh(ai[j] + P.bih[n+2*H] + r*(ah[j] + P.bhh[n+2*H]));
          hnext[j] = (1.f - u)*nn + u*sh_h[row*KP+n];
        }
      }
    }
    __syncthreads();
    #pragma unroll
    for (int j = 0; j < 13; ++j) {
      int n = ug + 8*j;
      if (n < H) sh_h[row*KP+n] = hnext[j];
    }
    __syncthreads();
  } // t

  // ---- reduce kl/nll: wave shuffle -> LDS -> one atomicAdd per block
  for (int off = 32; off > 0; off >>= 1) {
    kl_acc  += __shfl_down(kl_acc,  off);
    nll_acc += __shfl_down(nll_acc, off);
  }
  if (row == 0) { sh_red[ug] = kl_acc; sh_red[8+ug] = nll_acc; }
  __syncthreads();
  if (tid == 0) {
    float ks = 0.f, ns = 0.f;
    #pragma unroll
    for (int w = 0; w < 8; ++w) { ks += sh_red[w]; ns += sh_red[8+w]; }
    atomicAdd(&P.out[0], ks * (1.f/(float)B));
    atomicAdd(&P.out[1], ns * (1.f/(float)B));
  }
}

} // namespace

extern "C" void kernel_launch(void* const* d_in, const int* in_sizes, int n_in,
                              void* d_out, int out_size, void* d_ws, size_t ws_size,
                              hipStream_t stream)
{
  Params p;
  const float* const* f = (const float* const*)d_in;
  p.x=f[0];    p.eps=f[1];
  p.Wpx=f[2];  p.bpx=f[3];   p.Wpz=f[4];   p.bpz=f[5];
  p.Wp1=f[6];  p.bp1=f[7];   p.Wp_mu=f[8]; p.bp_mu=f[9];
  p.Wp_sig=f[10]; p.bp_sig=f[11];
  p.We1=f[12]; p.be1=f[13];  p.We_mu=f[14]; p.be_mu=f[15];
  p.We_sig=f[16]; p.be_sig=f[17];
  p.Wd1=f[18]; p.bd1=f[19];  p.Wd2=f[20];  p.bd2=f[21];
  p.Wd3=f[22]; p.bd3=f[23];
  p.Wih=f[24]; p.Whh=f[25];  p.bih=f[26];  p.bhh=f[27];
  p.out = (float*)d_out;

  hipMemsetAsync(d_out, 0, 2*sizeof(float), stream);
  vrnn_kernel<<<dim3(B/ROWS), dim3(NTH), 0, stream>>>(p);
}

// Round 2
// 863.767 us; speedup vs baseline: 19.2457x; 19.2457x over previous
//
#include <hip/hip_runtime.h>
#include <math.h>

#define DEVFN __device__ __forceinline__

namespace {

typedef __bf16 bf16x8 __attribute__((ext_vector_type(8)));
typedef float  f32x4  __attribute__((ext_vector_type(4)));

constexpr int T = 28, B = 16384, X = 28, H = 100, Z = 16;
constexpr int ROWS = 64;          // batch rows per block (M), 256 blocks
constexpr int NTH  = 512;         // 8 waves
constexpr int ST   = 136;         // bf16 LDS stride for 128-col activation buffers (+8 pad -> 272B rows, 68-word period)
constexpr int XST  = 40;          // bf16 LDS stride for X/Z (32-col) buffers (80B rows, 16B aligned)
constexpr float KEPS = 1e-10f;

// ---- weight-fragment table (1 frag = 16x32 B-tile = 64 lanes x 16B = 1024B) ----
constexpr int FB_PX   = 0;    // 7   KT=1
constexpr int FB_HE   = 7;    // 56  KT=8 (concat px|h)
constexpr int FB_EMU  = 63;   // 4   KT=4
constexpr int FB_ESIG = 67;   // 4
constexpr int FB_HP   = 71;   // 28  KT=4
constexpr int FB_PMU  = 99;   // 4
constexpr int FB_PSIG = 103;  // 4
constexpr int FB_PZ   = 107;  // 7   KT=1
constexpr int FB_HD1  = 114;  // 56  KT=8 (concat pz|h)
constexpr int FB_HD2  = 170;  // 28  KT=4
constexpr int FB_PRB  = 198;  // 8   KT=4 (Nt=2)
constexpr int FB_GIR  = 206;  // 56  KT=8 (concat pz|px)
constexpr int FB_GIU  = 262;  // 56
constexpr int FB_GIN  = 318;  // 56
constexpr int FB_GHR  = 374;  // 28  KT=4
constexpr int FB_GHU  = 402;  // 28
constexpr int FB_GHN  = 430;  // 28
constexpr int NFRAG   = 458;  // 469 KB in d_ws

struct Params {
  const float *x,*eps,*Wpx,*bpx,*Wpz,*bpz,*Wp1,*bp1,*Wp_mu,*bp_mu,*Wp_sig,*bp_sig,
              *We1,*be1,*We_mu,*be_mu,*We_sig,*be_sig,*Wd1,*bd1,*Wd2,*bd2,*Wd3,*bd3,
              *Wih,*Whh,*bih,*bhh;
  float *out;
};

DEVFN float fsigmoid(float v){ return 1.f/(1.f+__expf(-v)); }
DEVFN float fsoftplus(float v){ return (v > 15.f) ? v : log1pf(__expf(v)); }
DEVFN float ftanh(float v){
  v = fminf(fmaxf(v,-15.f),15.f);
  float e = __expf(2.f*v);
  return (e-1.f)/(e+1.f);
}

DEVFN f32x4 MFMA(bf16x8 a, bf16x8 b, f32x4 c){
  return __builtin_amdgcn_mfma_f32_16x16x32_bf16(a, b, c, 0, 0, 0);
}

// ---------------- weight prep: fp32 -> bf16 B-fragments in d_ws ----------------
// B[k][n] = W[n][k-space]; lane l holds j=0..7 of B[kc*32+(l>>4)*8+j][nt*16+(l&15)]
__global__ void prep_kernel(Params P, __bf16* FRW)
{
  const int f = blockIdx.x, l = threadIdx.x;
  const int bases[18] = {FB_PX,FB_HE,FB_EMU,FB_ESIG,FB_HP,FB_PMU,FB_PSIG,FB_PZ,FB_HD1,
                         FB_HD2,FB_PRB,FB_GIR,FB_GIU,FB_GIN,FB_GHR,FB_GHU,FB_GHN,NFRAG};
  int li = 0;
  while (f >= bases[li+1]) ++li;

  const float* W; int KT, N, roff, wstr, vK, mode;
  switch (li) {
    case 0:  W=P.Wpx;    KT=1; N=100; roff=0;   wstr=28;  vK=28;  mode=0; break;
    case 1:  W=P.We1;    KT=8; N=100; roff=0;   wstr=200; vK=100; mode=1; break;
    case 2:  W=P.We_mu;  KT=4; N=16;  roff=0;   wstr=100; vK=100; mode=0; break;
    case 3:  W=P.We_sig; KT=4; N=16;  roff=0;   wstr=100; vK=100; mode=0; break;
    case 4:  W=P.Wp1;    KT=4; N=100; roff=0;   wstr=100; vK=100; mode=0; break;
    case 5:  W=P.Wp_mu;  KT=4; N=16;  roff=0;   wstr=100; vK=100; mode=0; break;
    case 6:  W=P.Wp_sig; KT=4; N=16;  roff=0;   wstr=100; vK=100; mode=0; break;
    case 7:  W=P.Wpz;    KT=1; N=100; roff=0;   wstr=16;  vK=16;  mode=0; break;
    case 8:  W=P.Wd1;    KT=8; N=100; roff=0;   wstr=200; vK=100; mode=1; break;
    case 9:  W=P.Wd2;    KT=4; N=100; roff=0;   wstr=100; vK=100; mode=0; break;
    case 10: W=P.Wd3;    KT=4; N=28;  roff=0;   wstr=100; vK=100; mode=0; break;
    case 11: W=P.Wih;    KT=8; N=100; roff=0;   wstr=200; vK=100; mode=1; break;
    case 12: W=P.Wih;    KT=8; N=100; roff=100; wstr=200; vK=100; mode=1; break;
    case 13: W=P.Wih;    KT=8; N=100; roff=200; wstr=200; vK=100; mode=1; break;
    case 14: W=P.Whh;    KT=4; N=100; roff=0;   wstr=100; vK=100; mode=0; break;
    case 15: W=P.Whh;    KT=4; N=100; roff=100; wstr=100; vK=100; mode=0; break;
    default: W=P.Whh;    KT=4; N=100; roff=200; wstr=100; vK=100; mode=0; break;
  }
  const int idx = f - bases[li];
  const int nt = idx / KT, kc = idx % KT;
  const int n  = nt*16 + (l & 15);

  bf16x8 v;
  #pragma unroll
  for (int j = 0; j < 8; ++j) {
    int kk  = (mode ? (kc & 3) : kc)*32 + ((l >> 4)*8) + j;
    int col = mode ? ((kc < 4 ? 0 : 100) + kk) : kk;
    float w = (n < N && kk < vK) ? W[(size_t)(roff + n)*wstr + col] : 0.f;
    v[j] = (__bf16)w;
  }
  *((bf16x8*)FRW + (size_t)f*64 + l) = v;
}

// ---------------- main kernel helpers ----------------
template<int NC>
DEVFN void load_afrags(bf16x8 (&af)[NC], const __bf16* A, int stride, int mt, int lane)
{
  const __bf16* p = A + (size_t)(mt*16 + (lane & 15))*stride + ((lane >> 4)*8);
  #pragma unroll
  for (int kc = 0; kc < NC; ++kc) af[kc] = *(const bf16x8*)(p + kc*32);
}

// standard H-output layer: 7 N-tiles, relu epilogue, bf16 dst (stride ST)
template<int KT, int NA>
DEVFN void layer7(const bf16x8 (&af)[NA], const bf16x8* FRbase, const float* bias,
                  __bf16* dst, int wv, int lane)
{
  const int mt = wv & 3;
  for (int nt = (wv >> 2); nt < 7; nt += 2) {
    f32x4 acc = {0.f,0.f,0.f,0.f};
    const bf16x8* wf = FRbase + (size_t)nt*KT*64 + lane;
    #pragma unroll
    for (int kc = 0; kc < KT; ++kc) acc = MFMA(af[kc], wf[kc*64], acc);
    const int col = nt*16 + (lane & 15);
    if (col < H) {
      const float b = bias[col];
      const int rbase = mt*16 + ((lane >> 4)*4);
      #pragma unroll
      for (int r = 0; r < 4; ++r) {
        float v = acc[r] + b;
        dst[(size_t)(rbase + r)*ST + col] = (__bf16)fmaxf(v, 0.f);
      }
    }
  }
}

template<int KT>
DEVFN f32x4 head4(const bf16x8 (&af)[KT], const bf16x8* FRbase, int lane)
{
  f32x4 acc = {0.f,0.f,0.f,0.f};
  #pragma unroll
  for (int kc = 0; kc < KT; ++kc) acc = MFMA(af[kc], FRbase[kc*64 + lane], acc);
  return acc;
}

__global__ __launch_bounds__(NTH, 2) void vrnn_kernel(Params P, const __bf16* FRW)
{
  __shared__ alignas(16) __bf16 sPX[ROWS*ST];
  __shared__ alignas(16) __bf16 sPZ[ROWS*ST];
  __shared__ alignas(16) __bf16 sT1[ROWS*ST];
  __shared__ alignas(16) __bf16 sT2[ROWS*ST];
  __shared__ alignas(16) __bf16 sH [2*ROWS*ST];
  __shared__ alignas(16) __bf16 sX [ROWS*XST];
  __shared__ alignas(16) __bf16 sZ [ROWS*XST];
  __shared__ float sEMU [ROWS*18];
  __shared__ float sESIG[ROWS*18];
  __shared__ float sPMU [ROWS*18];
  __shared__ float sPSIG[ROWS*18];
  __shared__ float sred[16];

  const bf16x8* FR = (const bf16x8*)FRW;
  const int tid  = threadIdx.x;
  const int lane = tid & 63;
  const int wv   = tid >> 6;
  const int mt   = wv & 3;
  const int gr0  = blockIdx.x * ROWS;

  for (int i = tid; i < ROWS*ST; i += NTH) {
    sPX[i]=(__bf16)0.f; sPZ[i]=(__bf16)0.f; sT1[i]=(__bf16)0.f; sT2[i]=(__bf16)0.f;
    sH[i]=(__bf16)0.f;  sH[ROWS*ST+i]=(__bf16)0.f;
  }
  for (int i = tid; i < ROWS*XST; i += NTH) { sX[i]=(__bf16)0.f; sZ[i]=(__bf16)0.f; }
  __syncthreads();

  float kl = 0.f, nll = 0.f;

  for (int t = 0; t < T; ++t) {
    __bf16* Hc = sH + (t & 1)*ROWS*ST;
    __bf16* Hn = sH + ((t + 1) & 1)*ROWS*ST;

    // stage x[t] (coalesced fp32 read -> bf16 LDS)
    for (int i = tid; i < ROWS*X; i += NTH) {
      int r = i / X, c = i - r*X;
      sX[r*XST + c] = (__bf16)P.x[((size_t)t*B + gr0 + r)*X + c];
    }
    __syncthreads();

    // P1: px = relu(x Wpx^T + b) ; hp = relu(h Wp1^T + b)
    {
      bf16x8 ax[1]; load_afrags(ax, sX, XST, mt, lane);
      layer7<1>(ax, FR + (size_t)FB_PX*64, P.bpx, sPX, wv, lane);
      bf16x8 ah[4]; load_afrags(ah, Hc, ST, mt, lane);
      layer7<4>(ah, FR + (size_t)FB_HP*64, P.bp1, sT2, wv, lane);
    }
    __syncthreads();

    // P2: he = relu([px|h] We1^T + b) -> T1
    {
      bf16x8 af[8];
      { bf16x8 a0[4]; load_afrags(a0, sPX, ST, mt, lane);
        bf16x8 a1[4]; load_afrags(a1, Hc,  ST, mt, lane);
        #pragma unroll
        for (int k = 0; k < 4; ++k) { af[k]=a0[k]; af[4+k]=a1[k]; } }
      layer7<8>(af, FR + (size_t)FB_HE*64, P.be1, sT1, wv, lane);
    }
    __syncthreads();

    // P3: four Z-heads (waves 0-3: mu's, waves 4-7: sig's)
    {
      bf16x8 a1[4]; load_afrags(a1, sT1, ST, mt, lane);
      bf16x8 a2[4]; load_afrags(a2, sT2, ST, mt, lane);
      const bool lo = (wv < 4);
      f32x4 e = head4(a1, FR + (size_t)(lo ? FB_EMU : FB_ESIG)*64, lane);
      f32x4 p = head4(a2, FR + (size_t)(lo ? FB_PMU : FB_PSIG)*64, lane);
      const int n = lane & 15;
      const int rbase = mt*16 + ((lane >> 4)*4);
      if (lo) {
        #pragma unroll
        for (int r = 0; r < 4; ++r) {
          sEMU[(rbase+r)*18 + n] = e[r] + P.be_mu[n];
          sPMU[(rbase+r)*18 + n] = p[r] + P.bp_mu[n];
        }
      } else {
        #pragma unroll
        for (int r = 0; r < 4; ++r) {
          sESIG[(rbase+r)*18 + n] = fsoftplus(e[r] + P.be_sig[n]);
          sPSIG[(rbase+r)*18 + n] = fsoftplus(p[r] + P.bp_sig[n]);
        }
      }
    }
    __syncthreads();

    // P3e: z = mu_e + sqrt(sig_e)*eps ; KL accumulation (fp32)
    for (int i = tid; i < ROWS*Z; i += NTH) {
      int r = i >> 4, zi = i & 15;
      float es = sESIG[r*18 + zi], em = sEMU[r*18 + zi];
      float ev = P.eps[((size_t)t*B + gr0 + r)*Z + zi];
      sZ[r*XST + zi] = (__bf16)(em + sqrtf(es)*ev);
      float ps = sPSIG[r*18 + zi] + KEPS;
      float dm = em - sPMU[r*18 + zi];
      kl += 0.5f*(2.f*__logf(ps) - 2.f*__logf(es) + (es*es + dm*dm)/(ps*ps) - 1.f);
    }
    __syncthreads();

    // P4: pz = relu(z Wpz^T + b)
    {
      bf16x8 az[1]; load_afrags(az, sZ, XST, mt, lane);
      layer7<1>(az, FR + (size_t)FB_PZ*64, P.bpz, sPZ, wv, lane);
    }
    __syncthreads();

    // P5: hd1 = relu([pz|h] Wd1^T + b) -> T1 ; fused GRU -> Hn
    {
      bf16x8 af[8];
      { bf16x8 a0[4]; load_afrags(a0, sPZ, ST, mt, lane);
        bf16x8 a1[4]; load_afrags(a1, Hc,  ST, mt, lane);
        #pragma unroll
        for (int k = 0; k < 4; ++k) { af[k]=a0[k]; af[4+k]=a1[k]; } }
      layer7<8>(af, FR + (size_t)FB_HD1*64, P.bd1, sT1, wv, lane);

      bf16x8 afx[4]; load_afrags(afx, sPX, ST, mt, lane);
      for (int c = (wv >> 2); c < 7; c += 2) {
        f32x4 gr={0.f,0.f,0.f,0.f}, gu={0.f,0.f,0.f,0.f}, gn={0.f,0.f,0.f,0.f};
        f32x4 hr={0.f,0.f,0.f,0.f}, hu={0.f,0.f,0.f,0.f}, hn={0.f,0.f,0.f,0.f};
        const bf16x8* wr = FR + (size_t)(FB_GIR + c*8)*64 + lane;
        const bf16x8* wu = FR + (size_t)(FB_GIU + c*8)*64 + lane;
        const bf16x8* wn = FR + (size_t)(FB_GIN + c*8)*64 + lane;
        #pragma unroll
        for (int kc = 0; kc < 4; ++kc) {        // gi part 1: pz
          bf16x8 a = af[kc];
          gr = MFMA(a, wr[kc*64], gr); gu = MFMA(a, wu[kc*64], gu); gn = MFMA(a, wn[kc*64], gn);
        }
        #pragma unroll
        for (int kc = 0; kc < 4; ++kc) {        // gi part 2: px
          bf16x8 a = afx[kc];
          gr = MFMA(a, wr[(4+kc)*64], gr); gu = MFMA(a, wu[(4+kc)*64], gu); gn = MFMA(a, wn[(4+kc)*64], gn);
        }
        const bf16x8* vr = FR + (size_t)(FB_GHR + c*4)*64 + lane;
        const bf16x8* vu = FR + (size_t)(FB_GHU + c*4)*64 + lane;
        const bf16x8* vn = FR + (size_t)(FB_GHN + c*4)*64 + lane;
        #pragma unroll
        for (int kc = 0; kc < 4; ++kc) {        // gh: h
          bf16x8 a = af[4+kc];
          hr = MFMA(a, vr[kc*64], hr); hu = MFMA(a, vu[kc*64], hu); hn = MFMA(a, vn[kc*64], hn);
        }
        const int n = c*16 + (lane & 15);
        if (n < H) {
          const float bir=P.bih[n], biu=P.bih[n+H], bin=P.bih[n+2*H];
          const float bhr=P.bhh[n], bhu=P.bhh[n+H], bhn=P.bhh[n+2*H];
          const int rbase = mt*16 + ((lane >> 4)*4);
          #pragma unroll
          for (int r = 0; r < 4; ++r) {
            float rr = fsigmoid(gr[r] + bir + hr[r] + bhr);
            float uu = fsigmoid(gu[r] + biu + hu[r] + bhu);
            float nn = ftanh(gn[r] + bin + rr*(hn[r] + bhn));
            float ho = (float)Hc[(size_t)(rbase+r)*ST + n];
            Hn[(size_t)(rbase+r)*ST + n] = (__bf16)((1.f-uu)*nn + uu*ho);
          }
        }
      }
    }
    __syncthreads();

    // P6: hd2 = relu(T1 Wd2^T + b) -> T2
    {
      bf16x8 af[4]; load_afrags(af, sT1, ST, mt, lane);
      layer7<4>(af, FR + (size_t)FB_HD2*64, P.bd2, sT2, wv, lane);
    }
    __syncthreads();

    // P7: probs = sigmoid(T2 Wd3^T + b) ; NLL (fp32 x from global)
    {
      bf16x8 af[4]; load_afrags(af, sT2, ST, mt, lane);
      const int nt = wv >> 2;
      f32x4 acc = head4(af, FR + (size_t)(FB_PRB + nt*4)*64, lane);
      const int n = nt*16 + (lane & 15);
      if (n < X) {
        const float b = P.bd3[n];
        const int rbase = mt*16 + ((lane >> 4)*4);
        #pragma unroll
        for (int r = 0; r < 4; ++r) {
          float p  = fsigmoid(acc[r] + b);
          float xv = P.x[((size_t)t*B + gr0 + rbase + r)*X + n];
          nll -= xv*__logf(p + KEPS) + (1.f - xv)*__logf(1.f - p + KEPS);
        }
      }
    }
    __syncthreads();
  } // t

  // reduce kl/nll: wave shuffle -> LDS -> one atomicAdd per block
  for (int off = 32; off > 0; off >>= 1) {
    kl  += __shfl_down(kl,  off);
    nll += __shfl_down(nll, off);
  }
  if (lane == 0) { sred[wv] = kl; sred[8 + wv] = nll; }
  __syncthreads();
  if (tid == 0) {
    float ks = 0.f, ns = 0.f;
    #pragma unroll
    for (int w = 0; w < 8; ++w) { ks += sred[w]; ns += sred[8 + w]; }
    atomicAdd(&P.out[0], ks * (1.f/(float)B));
    atomicAdd(&P.out[1], ns * (1.f/(float)B));
  }
}

} // namespace

extern "C" void kernel_launch(void* const* d_in, const int* in_sizes, int n_in,
                              void* d_out, int out_size, void* d_ws, size_t ws_size,
                              hipStream_t stream)
{
  Params p;
  const float* const* f = (const float* const*)d_in;
  p.x=f[0];    p.eps=f[1];
  p.Wpx=f[2];  p.bpx=f[3];   p.Wpz=f[4];   p.bpz=f[5];
  p.Wp1=f[6];  p.bp1=f[7];   p.Wp_mu=f[8]; p.bp_mu=f[9];
  p.Wp_sig=f[10]; p.bp_sig=f[11];
  p.We1=f[12]; p.be1=f[13];  p.We_mu=f[14]; p.be_mu=f[15];
  p.We_sig=f[16]; p.be_sig=f[17];
  p.Wd1=f[18]; p.bd1=f[19];  p.Wd2=f[20];  p.bd2=f[21];
  p.Wd3=f[22]; p.bd3=f[23];
  p.Wih=f[24]; p.Whh=f[25];  p.bih=f[26];  p.bhh=f[27];
  p.out = (float*)d_out;

  hipMemsetAsync(d_out, 0, 2*sizeof(float), stream);
  prep_kernel<<<dim3(NFRAG), dim3(64), 0, stream>>>(p, (__bf16*)d_ws);
  vrnn_kernel<<<dim3(B/ROWS), dim3(NTH), 0, stream>>>(p, (const __bf16*)d_ws);
}